// Round 1
// baseline (155.359 us; speedup 1.0000x reference)
//
#include <hip/hip_runtime.h>
#include <math.h>

#define IC 64
#define OC 128
#define HH 56
#define WW 56
#define BATCH 16
#define HP 58              // padded spatial
#define NPIX (BATCH*HH*WW) // 50176
#define SPAN 576
#define TSIZE 8

typedef unsigned short ushort_t;
typedef unsigned int uint_t;
typedef __attribute__((ext_vector_type(8))) __bf16 bf16x8;
typedef __attribute__((ext_vector_type(4))) float f32x4;

__device__ __forceinline__ ushort_t bf16_rne(float f) {
  uint_t u = __builtin_bit_cast(uint_t, f);
  u += 0x7FFFu + ((u >> 16) & 1u);
  return (ushort_t)(u >> 16);
}

// ---------------- kernel 1: NCHW fp32 -> padded NHWC bf16, zero counts -------
__global__ void pad_kernel(const float* __restrict__ x, ushort_t* __restrict__ xpad,
                           int* __restrict__ counts) {
  int tid = threadIdx.x;
  int idx = blockIdx.x * 256 + tid;
  if (blockIdx.x == 0 && tid < TSIZE) counts[tid] = 0;
  if (idx >= BATCH * HP * HP) return;
  int b = idx / (HP * HP);
  int rem = idx % (HP * HP);
  int y = rem / HP, xw = rem % HP;
  int h = y - 1, w = xw - 1;
  bool inb = ((unsigned)h < (unsigned)HH) && ((unsigned)w < (unsigned)WW);
  int off = inb ? (h * WW + w) : 0;
  const float* src = x + (size_t)b * IC * HH * WW + off;
  uint_t* dst = (uint_t*)(xpad + (size_t)idx * IC);
  #pragma unroll
  for (int c2 = 0; c2 < IC / 2; ++c2) {
    float f0 = inb ? src[(2 * c2) * (HH * WW)] : 0.0f;
    float f1 = inb ? src[(2 * c2 + 1) * (HH * WW)] : 0.0f;
    dst[c2] = (uint_t)bf16_rne(f0) | ((uint_t)bf16_rne(f1) << 16);
  }
}

// ---------------- kernel 2: patch voting (fp32) ------------------------------
// block = 256 threads = 64 pixels x 4 channel-quarters
__global__ void vote_kernel(const float* __restrict__ x, const float* __restrict__ a,
                            const float* __restrict__ bptr, int* __restrict__ counts) {
  __shared__ float partial[256];
  __shared__ int hist[TSIZE];
  int t = threadIdx.x;
  if (t < TSIZE) hist[t] = 0;
  int pl = t & 63, cq = t >> 6;
  int n = blockIdx.x * 64 + pl;
  int b = n / (HH * WW);
  int rem = n % (HH * WW);
  int h = rem / WW, w = rem % WW;
  const float* xb = x + (size_t)b * IC * HH * WW;
  float s = 0.0f;
  for (int c = cq * 16; c < cq * 16 + 16; ++c) {
    const float* xc = xb + c * (HH * WW);
    const float* ac = a + c * 9;
    #pragma unroll
    for (int kh = 0; kh < 3; ++kh) {
      int y = h + kh - 1;
      if ((unsigned)y < (unsigned)HH) {
        #pragma unroll
        for (int kw = 0; kw < 3; ++kw) {
          int xx = w + kw - 1;
          if ((unsigned)xx < (unsigned)WW) s += ac[kh * 3 + kw] * xc[y * WW + xx];
        }
      }
    }
  }
  partial[t] = s;
  __syncthreads();
  if (t < 64) {
    float v = partial[t] + partial[t + 64] + partial[t + 128] + partial[t + 192];
    float tail = 0.5f * (a[576] + a[577] + a[578] + a[579] + a[580]);
    int hi = (int)floorf((v + tail + bptr[0]) / 2.5f);
    int r = hi % TSIZE;
    if (r < 0) r = -r;
    atomicAdd(&hist[r], 1);
  }
  __syncthreads();
  if (t < TSIZE) atomicAdd(&counts[t], hist[t]);
}

// ---------------- kernel 3: kernel hashing + bucket argmax + factor ----------
__global__ void hash_kernel(const float* __restrict__ kernels, const float* __restrict__ a,
                            const float* __restrict__ bptr, const int* __restrict__ counts,
                            float* __restrict__ factor) {
  __shared__ int bucket_s, cnt_s;
  int t = threadIdx.x;  // 128 threads
  if (t == 0) {
    int best = counts[0], bi = 0;
    #pragma unroll
    for (int i = 1; i < TSIZE; ++i)
      if (counts[i] > best) { best = counts[i]; bi = i; }  // strict > => first max (argmax)
    bucket_s = bi;
    cnt_s = 0;
  }
  const float* krow = kernels + (size_t)t * SPAN;
  float dot = 0.0f, n2 = 0.0f;
  for (int k = 0; k < SPAN; ++k) {
    float kv = krow[k];
    dot += kv * a[k];
    n2 += kv * kv;
  }
  // powers: ||k||^2^(2^i) for i=0..4 via repeated squaring
  float p = n2, hk = dot;
  #pragma unroll
  for (int i = 0; i < 5; ++i) { hk += p * a[SPAN + i]; p = p * p; }
  int hi = (int)floorf((hk + bptr[0]) / 2.5f);
  int r = hi % TSIZE;
  if (r < 0) r = -r;
  __syncthreads();
  int m = (r == bucket_s) ? 1 : 0;
  if (m) atomicAdd(&cnt_s, 1);
  __syncthreads();
  int cnt = cnt_s;
  factor[t] = (cnt > 0) ? (m ? 128.0f / (float)cnt : 0.0f) : 1.0f;
}

// ---------------- kernel 4: W2 = bf16(kernels * factor), (tap, c)-major K ----
__global__ void w2_kernel(const float* __restrict__ kernels, const float* __restrict__ factor,
                          ushort_t* __restrict__ w2) {
  int idx = blockIdx.x * 256 + threadIdx.x;  // < 73728 (exact)
  int oc = idx / SPAN, k = idx % SPAN;
  int tap = k >> 6, c = k & 63;              // K reordered: (kh,kw,c)
  float v = kernels[(size_t)oc * SPAN + c * 9 + tap] * factor[oc];
  w2[idx] = bf16_rne(v);
}

// ---------------- kernel 5: implicit GEMM, 128x128 tile, BK=64 (one tap) -----
// C[128, 50176] = W2[128,576] @ P[576,50176];  P gathered from padded NHWC bf16.
// Staging via global_load_lds width=16; XOR chunk swizzle applied on the GLOBAL
// source side (LDS write side is rigid base+lane*16) so fragment ds_read_b128
// is bank-conflict-free.
__global__ __launch_bounds__(256, 2)
void gemm_kernel(const ushort_t* __restrict__ w2, const ushort_t* __restrict__ xpad,
                 float* __restrict__ out) {
  __shared__ ushort_t As[128 * 64];
  __shared__ ushort_t Bs[128 * 64];
  const int tid = threadIdx.x;
  const int wave = tid >> 6, lane = tid & 63;
  const int n0 = blockIdx.x * 128;
  const int wm = (wave >> 1) * 64;  // wave M-offset
  const int wn = (wave & 1) * 64;   // wave N-offset

  const int srow = lane >> 3;             // 0..7: row within 8-row staging group
  const int sch = (lane & 7) ^ srow;      // swizzled logical chunk this lane fetches

  int agbase[4], bgbase[4], lbase[4];
  #pragma unroll
  for (int i = 0; i < 4; ++i) {
    int row = wave * 32 + i * 8 + srow;   // tile-local row / pixel 0..127
    agbase[i] = row * SPAN + sch * 8;
    int n = n0 + row;
    int b = n / (HH * WW);
    int rem = n % (HH * WW);
    int h = rem / WW, w = rem % WW;
    bgbase[i] = ((b * HP + h) * HP + w) * IC + sch * 8;
    lbase[i] = (wave * 32 + i * 8) * 64;  // LDS short offset, = byte base/2
  }

  f32x4 acc[4][4] = {};

  for (int tap = 0; tap < 9; ++tap) {
    const int kh = tap / 3, kw = tap % 3;
    const int toffA = tap * 64;
    const int toffB = (kh * HP + kw) * IC;
    __syncthreads();  // previous tile fully consumed
    #pragma unroll
    for (int i = 0; i < 4; ++i) {
      __builtin_amdgcn_global_load_lds(
          (const __attribute__((address_space(1))) void*)(w2 + agbase[i] + toffA),
          (__attribute__((address_space(3))) void*)(As + lbase[i]), 16, 0, 0);
      __builtin_amdgcn_global_load_lds(
          (const __attribute__((address_space(1))) void*)(xpad + bgbase[i] + toffB),
          (__attribute__((address_space(3))) void*)(Bs + lbase[i]), 16, 0, 0);
    }
    __syncthreads();  // staging drained (compiler emits vmcnt(0) before barrier)
    #pragma unroll
    for (int kk = 0; kk < 2; ++kk) {
      const int jf = kk * 4 + (lane >> 4);  // logical k-chunk for this quad
      bf16x8 af[4], bfr[4];
      #pragma unroll
      for (int m = 0; m < 4; ++m) {
        int row = wm + m * 16 + (lane & 15);
        int slot = row * 8 + (jf ^ (row & 7));
        af[m] = *(const bf16x8*)(As + slot * 8);
      }
      #pragma unroll
      for (int n = 0; n < 4; ++n) {
        int col = wn + n * 16 + (lane & 15);
        int slot = col * 8 + (jf ^ (col & 7));
        bfr[n] = *(const bf16x8*)(Bs + slot * 8);
      }
      #pragma unroll
      for (int m = 0; m < 4; ++m)
        #pragma unroll
        for (int n = 0; n < 4; ++n)
          acc[m][n] = __builtin_amdgcn_mfma_f32_16x16x32_bf16(af[m], bfr[n], acc[m][n], 0, 0, 0);
    }
  }

  // epilogue: C/D layout col=lane&15 (pixel), row=(lane>>4)*4+r (oc)
  #pragma unroll
  for (int n = 0; n < 4; ++n) {
    int np = n0 + wn + n * 16 + (lane & 15);
    int b = np / (HH * WW);
    int rem = np % (HH * WW);
    float* obase = out + ((size_t)b * OC) * (HH * WW) + rem;
    #pragma unroll
    for (int m = 0; m < 4; ++m) {
      int ocb = wm + m * 16 + (lane >> 4) * 4;
      #pragma unroll
      for (int r = 0; r < 4; ++r) {
        obase[(size_t)(ocb + r) * (HH * WW)] = acc[m][n][r];
      }
    }
  }
}

extern "C" void kernel_launch(void* const* d_in, const int* in_sizes, int n_in,
                              void* d_out, int out_size, void* d_ws, size_t ws_size,
                              hipStream_t stream) {
  (void)in_sizes; (void)n_in; (void)out_size; (void)ws_size;
  const float* x = (const float*)d_in[0];       // [16,64,56,56]
  const float* kernels = (const float*)d_in[1]; // [128,576]
  const float* a = (const float*)d_in[2];       // [581]
  const float* b = (const float*)d_in[3];       // scalar
  // d_in[4] = mode (unused by reference math)
  float* out = (float*)d_out;                   // [16,128,56,56] fp32

  char* ws = (char*)d_ws;
  int* counts = (int*)ws;                          // 32 B
  float* factor = (float*)(ws + 64);               // 512 B
  ushort_t* w2 = (ushort_t*)(ws + 1024);           // 147456 B
  ushort_t* xpad = (ushort_t*)(ws + 1024 + 147456);// 6,889,472 B  (~6.7 MB total)

  pad_kernel<<<211, 256, 0, stream>>>(x, xpad, counts);
  vote_kernel<<<NPIX / 64, 256, 0, stream>>>(x, a, b, counts);
  hash_kernel<<<1, 128, 0, stream>>>(kernels, a, b, counts, factor);
  w2_kernel<<<288, 256, 0, stream>>>(kernels, factor, w2);
  gemm_kernel<<<NPIX / 128, 256, 0, stream>>>(w2, xpad, out);
}

// Round 2
// 144.411 us; speedup vs baseline: 1.0758x; 1.0758x over previous
//
#include <hip/hip_runtime.h>
#include <math.h>

#define IC 64
#define OC 128
#define HH 56
#define WW 56
#define BATCH 16
#define HP 58              // padded spatial
#define NPIX (BATCH*HH*WW) // 50176
#define SPAN 576
#define TSIZE 8

typedef unsigned short ushort_t;
typedef unsigned int uint_t;
typedef __attribute__((ext_vector_type(8))) __bf16 bf16x8;
typedef __attribute__((ext_vector_type(4))) float f32x4;

__device__ __forceinline__ ushort_t bf16_rne(float f) {
  uint_t u = __builtin_bit_cast(uint_t, f);
  u += 0x7FFFu + ((u >> 16) & 1u);
  return (ushort_t)(u >> 16);
}

// ---------------- kernel 1: per-row dot/norm + bucket + bf16 repack ----------
// 128 blocks (one per OC row) x 256 threads. Coalesced reads; also zeroes counts.
__global__ void w2row_kernel(const float* __restrict__ kernels, const float* __restrict__ a,
                             const float* __restrict__ bptr, ushort_t* __restrict__ w2,
                             int* __restrict__ rbucket, int* __restrict__ counts) {
  const int r = blockIdx.x, t = threadIdx.x;
  if (r == 0 && t < TSIZE) counts[t] = 0;
  const float* row = kernels + (size_t)r * SPAN;
  float d = 0.0f, n2 = 0.0f;
  #pragma unroll
  for (int k0 = 0; k0 < 3; ++k0) {
    int k = k0 * 256 + t;
    if (k < SPAN) { float kv = row[k]; d += kv * a[k]; n2 += kv * kv; }
  }
  __shared__ float red0[256], red1[256];
  red0[t] = d; red1[t] = n2;
  __syncthreads();
  for (int s = 128; s > 0; s >>= 1) {
    if (t < s) { red0[t] += red0[t + s]; red1[t] += red1[t + s]; }
    __syncthreads();
  }
  if (t == 0) {
    float hk = red0[0], p = red1[0];
    #pragma unroll
    for (int i = 0; i < 5; ++i) { hk += p * a[SPAN + i]; p = p * p; }
    int hi = (int)floorf((hk + bptr[0]) / 2.5f);
    int rr = hi % TSIZE;
    if (rr < 0) rr = -rr;
    rbucket[r] = rr;
  }
  // repack K to (tap, c)-major, bf16 (factor applied later in gemm epilogue)
  #pragma unroll
  for (int j0 = 0; j0 < 3; ++j0) {
    int j = j0 * 256 + t;
    if (j < SPAN) {
      int tap = j >> 6, c = j & 63;
      w2[(size_t)r * SPAN + j] = bf16_rne(row[c * 9 + tap]);
    }
  }
}

// ---------------- kernel 2: NCHW fp32 -> padded NHWC bf16 --------------------
__global__ void pad_kernel(const float* __restrict__ x, ushort_t* __restrict__ xpad) {
  int idx = blockIdx.x * 256 + threadIdx.x;
  if (idx >= BATCH * HP * HP) return;
  int b = idx / (HP * HP);
  int rem = idx % (HP * HP);
  int y = rem / HP, xw = rem % HP;
  int h = y - 1, w = xw - 1;
  bool inb = ((unsigned)h < (unsigned)HH) && ((unsigned)w < (unsigned)WW);
  int off = inb ? (h * WW + w) : 0;
  const float* src = x + (size_t)b * IC * HH * WW + off;
  uint_t* dst = (uint_t*)(xpad + (size_t)idx * IC);
  #pragma unroll
  for (int c2 = 0; c2 < IC / 2; ++c2) {
    float f0 = inb ? src[(2 * c2) * (HH * WW)] : 0.0f;
    float f1 = inb ? src[(2 * c2 + 1) * (HH * WW)] : 0.0f;
    dst[c2] = (uint_t)bf16_rne(f0) | ((uint_t)bf16_rne(f1) << 16);
  }
}

// ---------------- kernel 3: patch voting (fp32) ------------------------------
// block = 256 threads = 64 pixels x 4 channel-quarters
__global__ void vote_kernel(const float* __restrict__ x, const float* __restrict__ a,
                            const float* __restrict__ bptr, int* __restrict__ counts) {
  __shared__ float partial[256];
  __shared__ int hist[TSIZE];
  int t = threadIdx.x;
  if (t < TSIZE) hist[t] = 0;
  int pl = t & 63, cq = t >> 6;
  int n = blockIdx.x * 64 + pl;
  int b = n / (HH * WW);
  int rem = n % (HH * WW);
  int h = rem / WW, w = rem % WW;
  const float* xb = x + (size_t)b * IC * HH * WW;
  float s = 0.0f;
  for (int c = cq * 16; c < cq * 16 + 16; ++c) {
    const float* xc = xb + c * (HH * WW);
    const float* ac = a + c * 9;
    #pragma unroll
    for (int kh = 0; kh < 3; ++kh) {
      int y = h + kh - 1;
      if ((unsigned)y < (unsigned)HH) {
        #pragma unroll
        for (int kw = 0; kw < 3; ++kw) {
          int xx = w + kw - 1;
          if ((unsigned)xx < (unsigned)WW) s += ac[kh * 3 + kw] * xc[y * WW + xx];
        }
      }
    }
  }
  partial[t] = s;
  __syncthreads();
  if (t < 64) {
    float v = partial[t] + partial[t + 64] + partial[t + 128] + partial[t + 192];
    float tail = 0.5f * (a[576] + a[577] + a[578] + a[579] + a[580]);
    int hi = (int)floorf((v + tail + bptr[0]) / 2.5f);
    int r = hi % TSIZE;
    if (r < 0) r = -r;
    atomicAdd(&hist[r], 1);
  }
  __syncthreads();
  if (t < TSIZE) atomicAdd(&counts[t], hist[t]);
}

// ---------------- kernel 4: implicit GEMM, 128x64 tile, BK=64 (one tap) ------
// C[128, 50176] = W2[128,576] @ P[576,50176];  P gathered from padded NHWC bf16.
// Factor (bucket select/scale) computed per-block in the epilogue from
// counts[8] + rbucket[128] — removes the serial hash kernel entirely.
__global__ __launch_bounds__(256, 4)
void gemm_kernel(const ushort_t* __restrict__ w2, const ushort_t* __restrict__ xpad,
                 const int* __restrict__ counts, const int* __restrict__ rbucket,
                 float* __restrict__ out) {
  __shared__ ushort_t As[128 * 64];   // 16 KB
  __shared__ ushort_t Bs[64 * 64];    //  8 KB
  __shared__ float factor_s[OC];
  __shared__ int cnt_s;
  const int tid = threadIdx.x;
  const int wave = tid >> 6, lane = tid & 63;
  const int n0 = blockIdx.x * 64;
  const int wm = wave * 32;           // wave M-offset (32 oc rows per wave)

  const int srow = lane >> 3;         // 0..7
  const int sch = (lane & 7) ^ srow;  // swizzled global chunk for this lane

  int agbase[4], bgbase[2];
  #pragma unroll
  for (int i = 0; i < 4; ++i) {
    int row = wm + i * 8 + srow;
    agbase[i] = row * SPAN + sch * 8;
  }
  #pragma unroll
  for (int i = 0; i < 2; ++i) {
    int brow = wave * 16 + i * 8 + srow;
    int n = n0 + brow;
    int b = n / (HH * WW);
    int rem = n % (HH * WW);
    int h = rem / WW, w = rem % WW;
    bgbase[i] = ((b * HP + h) * HP + w) * IC + sch * 8;
  }

  f32x4 acc[2][4] = {};

  for (int tap = 0; tap < 9; ++tap) {
    const int kh = tap / 3, kw = tap % 3;
    const int toffA = tap * 64;
    const int toffB = (kh * HP + kw) * IC;
    __syncthreads();  // previous tile consumed
    #pragma unroll
    for (int i = 0; i < 4; ++i)
      __builtin_amdgcn_global_load_lds(
          (const __attribute__((address_space(1))) void*)(w2 + agbase[i] + toffA),
          (__attribute__((address_space(3))) void*)(As + (wm + i * 8) * 64), 16, 0, 0);
    #pragma unroll
    for (int i = 0; i < 2; ++i)
      __builtin_amdgcn_global_load_lds(
          (const __attribute__((address_space(1))) void*)(xpad + bgbase[i] + toffB),
          (__attribute__((address_space(3))) void*)(Bs + (wave * 16 + i * 8) * 64), 16, 0, 0);
    __syncthreads();  // staging drained
    #pragma unroll
    for (int kk = 0; kk < 2; ++kk) {
      const int jf = kk * 4 + (lane >> 4);
      bf16x8 af[2], bfr[4];
      #pragma unroll
      for (int m = 0; m < 2; ++m) {
        int row = wm + m * 16 + (lane & 15);
        int slot = row * 8 + (jf ^ (row & 7));
        af[m] = *(const bf16x8*)(As + slot * 8);
      }
      #pragma unroll
      for (int n = 0; n < 4; ++n) {
        int col = n * 16 + (lane & 15);
        int slot = col * 8 + (jf ^ (col & 7));
        bfr[n] = *(const bf16x8*)(Bs + slot * 8);
      }
      #pragma unroll
      for (int m = 0; m < 2; ++m)
        #pragma unroll
        for (int n = 0; n < 4; ++n)
          acc[m][n] = __builtin_amdgcn_mfma_f32_16x16x32_bf16(af[m], bfr[n], acc[m][n], 0, 0, 0);
    }
  }

  // ---- factor: bucket argmax + row-mask count + scale (per block, ~free) ----
  if (tid == 0) cnt_s = 0;
  __syncthreads();
  int isin = 0;
  if (tid < OC) {
    int best = counts[0], bi = 0;
    #pragma unroll
    for (int i = 1; i < TSIZE; ++i) { int c = counts[i]; if (c > best) { best = c; bi = i; } }
    isin = (rbucket[tid] == bi) ? 1 : 0;
    if (isin) atomicAdd(&cnt_s, 1);
  }
  __syncthreads();
  if (tid < OC) {
    int cnt = cnt_s;
    factor_s[tid] = (cnt > 0) ? (isin ? 128.0f / (float)cnt : 0.0f) : 1.0f;
  }
  __syncthreads();

  // ---- epilogue: C/D layout col=lane&15 (pixel), row=(lane>>4)*4+r (oc) -----
  #pragma unroll
  for (int n = 0; n < 4; ++n) {
    int np = n0 + n * 16 + (lane & 15);
    int b = np / (HH * WW);
    int rem = np % (HH * WW);
    float* obase = out + ((size_t)b * OC) * (HH * WW) + rem;
    #pragma unroll
    for (int m = 0; m < 2; ++m) {
      int ocb = wm + m * 16 + (lane >> 4) * 4;
      #pragma unroll
      for (int r = 0; r < 4; ++r) {
        obase[(size_t)(ocb + r) * (HH * WW)] = acc[m][n][r] * factor_s[ocb + r];
      }
    }
  }
}

extern "C" void kernel_launch(void* const* d_in, const int* in_sizes, int n_in,
                              void* d_out, int out_size, void* d_ws, size_t ws_size,
                              hipStream_t stream) {
  (void)in_sizes; (void)n_in; (void)out_size; (void)ws_size;
  const float* x = (const float*)d_in[0];       // [16,64,56,56]
  const float* kernels = (const float*)d_in[1]; // [128,576]
  const float* a = (const float*)d_in[2];       // [581]
  const float* b = (const float*)d_in[3];       // scalar
  float* out = (float*)d_out;                   // [16,128,56,56] fp32

  char* ws = (char*)d_ws;
  int* counts = (int*)ws;                           // 32 B
  int* rbucket = (int*)(ws + 64);                   // 512 B
  ushort_t* w2 = (ushort_t*)(ws + 1024);            // 147456 B
  ushort_t* xpad = (ushort_t*)(ws + 1024 + 147456); // 6,889,472 B

  w2row_kernel<<<OC, 256, 0, stream>>>(kernels, a, b, w2, rbucket, counts);
  pad_kernel<<<211, 256, 0, stream>>>(x, xpad);
  vote_kernel<<<NPIX / 64, 256, 0, stream>>>(x, a, b, counts);
  gemm_kernel<<<NPIX / 64, 256, 0, stream>>>(w2, xpad, counts, rbucket, out);
}